// Round 8
// baseline (1020.212 us; speedup 1.0000x reference)
//
#include <hip/hip_runtime.h>

typedef unsigned short u16;
typedef unsigned int u32;
typedef __attribute__((ext_vector_type(8))) short bf16x8;
typedef __attribute__((ext_vector_type(4))) float f32x4;

#define SEQ 1024
#define DM 768
#define NH 12
#define HD2 64
#define NLAYER 4
#define NVOCAB 50257
#define BT 2048  // B*T

__device__ __forceinline__ u16 f2bf(float f) {
  union { float f; u32 u; } v; v.f = f;
  u32 r = v.u + 0x7FFFu + ((v.u >> 16) & 1u);
  return (u16)(r >> 16);
}
__device__ __forceinline__ float bf2f(u16 u) {
  union { u32 u; float f; } v; v.u = ((u32)u) << 16;
  return v.f;
}

__device__ __forceinline__ void glds16(const u16* g, u16* l) {
  __builtin_amdgcn_global_load_lds(
      (const __attribute__((address_space(1))) u32*)(const void*)g,
      (__attribute__((address_space(3))) u32*)(void*)l, 16, 0, 0);
}

// ---------------- embedding ----------------
__global__ void k_embed(const int* __restrict__ idx, const float* __restrict__ wte,
                        float* __restrict__ xf) {
  int r = blockIdx.x;
  int tok = idx[r];
  const float* s = wte + (size_t)tok * DM;
  float* d = xf + (size_t)r * DM;
  for (int c = threadIdx.x; c < DM; c += 256) d[c] = s[c];
}

// ---------------- rope trig tables: [SEQ][16] cos/sin ----------------
__global__ void k_trig(float* __restrict__ ctab, float* __restrict__ stab) {
  int gid = blockIdx.x * 256 + threadIdx.x;  // over SEQ*16
  int tt = gid >> 4, j = gid & 15;
  float inv = powf(10000.f, -(float)j * (1.f / 32.f));
  float ang = (float)tt * inv;
  ctab[gid] = cosf(ang);
  stab[gid] = sinf(ang);
}

// ------- transpose + f32->bf16: in[R,C] f32 -> out[C,R] bf16 (64x64 tile) ----
__global__ void k_cvtT(const float* __restrict__ in, u16* __restrict__ out,
                       int R, int C) {
  __shared__ u16 t[64][68];
  int c0 = blockIdx.x * 64, r0 = blockIdx.y * 64;  // R always multiple of 64
  int tx = threadIdx.x & 15, ty = threadIdx.x >> 4;
  int c = c0 + tx * 4;
#pragma unroll
  for (int i = 0; i < 4; ++i) {
    int r = r0 + ty + i * 16;
    float4 v = make_float4(0.f, 0.f, 0.f, 0.f);
    if (c + 3 < C) {
      v = *(const float4*)&in[(size_t)r * C + c];
    } else {
      if (c + 0 < C) v.x = in[(size_t)r * C + c];
      if (c + 1 < C) v.y = in[(size_t)r * C + c + 1];
      if (c + 2 < C) v.z = in[(size_t)r * C + c + 2];
      if (c + 3 < C) v.w = in[(size_t)r * C + c + 3];
    }
    t[ty + i * 16][tx * 4 + 0] = f2bf(v.x);
    t[ty + i * 16][tx * 4 + 1] = f2bf(v.y);
    t[ty + i * 16][tx * 4 + 2] = f2bf(v.z);
    t[ty + i * 16][tx * 4 + 3] = f2bf(v.w);
  }
  __syncthreads();
  int wl = threadIdx.x & 31, grp = threadIdx.x >> 5;
#pragma unroll
  for (int it = 0; it < 8; ++it) {
    int cc = it * 8 + grp;
    int gcol = c0 + cc;
    if (gcol < C) {
      u32 wv = (u32)t[2 * wl][cc] | ((u32)t[2 * wl + 1][cc] << 16);
      *(u32*)&out[(size_t)gcol * R + r0 + 2 * wl] = wv;
    }
  }
}

// ---------------- block reductions (256 thr = 4 waves) ----------------
__device__ __forceinline__ float bsum(float v, float* red) {
#pragma unroll
  for (int o = 32; o > 0; o >>= 1) v += __shfl_down(v, o);
  if ((threadIdx.x & 63) == 0) red[threadIdx.x >> 6] = v;
  __syncthreads();
  if (threadIdx.x == 0) red[4] = red[0] + red[1] + red[2] + red[3];
  __syncthreads();
  return red[4];
}

// ---------------- dual layernorm (both read same x) ----------------
__global__ void k_ln(const float* __restrict__ x, const float* __restrict__ g1,
                     const float* __restrict__ b1, const float* __restrict__ g2,
                     const float* __restrict__ b2, u16* __restrict__ o1,
                     u16* __restrict__ o2) {
  __shared__ float red[8];
  int r = blockIdx.x;
  int t = threadIdx.x;
  const float* xr = x + (size_t)r * DM;
  float v0 = xr[t], v1 = xr[t + 256], v2 = xr[t + 512];
  float mean = bsum(v0 + v1 + v2, red) * (1.f / DM);
  float d0 = v0 - mean, d1 = v1 - mean, d2 = v2 - mean;
  float var = bsum(d0 * d0 + d1 * d1 + d2 * d2, red) * (1.f / DM);
  float rstd = rsqrtf(var + 1e-5f);
  u16* p1 = o1 + (size_t)r * DM;
  p1[t]       = f2bf(d0 * rstd * g1[t]       + b1[t]);
  p1[t + 256] = f2bf(d1 * rstd * g1[t + 256] + b1[t + 256]);
  p1[t + 512] = f2bf(d2 * rstd * g1[t + 512] + b1[t + 512]);
  if (o2) {
    u16* p2 = o2 + (size_t)r * DM;
    p2[t]       = f2bf(d0 * rstd * g2[t]       + b2[t]);
    p2[t + 256] = f2bf(d1 * rstd * g2[t + 256] + b2[t + 256]);
    p2[t + 512] = f2bf(d2 * rstd * g2[t + 512] + b2[t + 512]);
  }
}

// ---------------- fused flash attention, glds-staged double-buffered K/V ----
__global__ void k_attn(const u16* __restrict__ qr, const u16* __restrict__ kr,
                       const u16* __restrict__ vT, u16* __restrict__ yb) {
  int ti = (int)gridDim.x - 1 - (int)blockIdx.x;  // big tiles first
  int bh = blockIdx.y;
  __shared__ u16 Ps[64 * 72];       // Q staging, then P tile (wave-private rows)
  __shared__ u16 Ks[2][4096];       // [64][64] XOR-swizzled
  __shared__ u16 Vs[2][4096];
  int tid = threadIdx.x;
  int rr = tid >> 2, cc = tid & 3;
  int w = tid >> 6, l = tid & 63;
  int rl = l & 15, g = l >> 4;
  {
    const u16* gq = qr + ((size_t)bh * SEQ + ti * 64 + rr) * HD2;
    *(uint4*)&Ps[rr * 72 + cc * 8]      = *(const uint4*)(gq + cc * 8);
    *(uint4*)&Ps[rr * 72 + cc * 8 + 32] = *(const uint4*)(gq + cc * 8 + 32);
  }
  int srow = w * 8 + (l >> 3);
  int gs = (l & 7) ^ (l >> 3);
  const u16* gkb = kr + (size_t)bh * SEQ * HD2;
  const u16* gvb = vT + (size_t)bh * HD2 * SEQ;
  glds16(gkb + (size_t)srow * 64 + gs * 8,        &Ks[0][w * 512]);
  glds16(gkb + (size_t)(32 + srow) * 64 + gs * 8, &Ks[0][2048 + w * 512]);
  glds16(gvb + (size_t)srow * SEQ + gs * 8,       &Vs[0][w * 512]);
  glds16(gvb + (size_t)(32 + srow) * SEQ + gs * 8,&Vs[0][2048 + w * 512]);
  __syncthreads();
  bf16x8 aq0 = *(const bf16x8*)&Ps[(w * 16 + rl) * 72 + g * 8];
  bf16x8 aq1 = *(const bf16x8*)&Ps[(w * 16 + rl) * 72 + 32 + g * 8];
  float m[4], lsum[4];
  f32x4 oacc[4] = {};
#pragma unroll
  for (int r2 = 0; r2 < 4; ++r2) { m[r2] = -3.0e38f; lsum[r2] = 0.f; }
  int qloc = w * 16 + g * 4;
  int sw = rl & 7;
  int cur = 0;
  for (int kt = 0; kt <= ti; ++kt) {
    if (kt < ti) {
      int nx = cur ^ 1;
      glds16(gkb + (size_t)((kt + 1) * 64 + srow) * 64 + gs * 8,      &Ks[nx][w * 512]);
      glds16(gkb + (size_t)((kt + 1) * 64 + 32 + srow) * 64 + gs * 8, &Ks[nx][2048 + w * 512]);
      glds16(gvb + (size_t)srow * SEQ + (kt + 1) * 64 + gs * 8,       &Vs[nx][w * 512]);
      glds16(gvb + (size_t)(32 + srow) * SEQ + (kt + 1) * 64 + gs * 8,&Vs[nx][2048 + w * 512]);
    }
    f32x4 s[4] = {};
    __builtin_amdgcn_s_setprio(1);
#pragma unroll
    for (int nt = 0; nt < 4; ++nt) {
      int r = (nt * 16 + rl) * 64;
      bf16x8 b0 = *(const bf16x8*)&Ks[cur][r + ((0 + g) ^ sw) * 8];
      bf16x8 b1 = *(const bf16x8*)&Ks[cur][r + ((4 + g) ^ sw) * 8];
      s[nt] = __builtin_amdgcn_mfma_f32_16x16x32_bf16(aq0, b0, s[nt], 0, 0, 0);
      s[nt] = __builtin_amdgcn_mfma_f32_16x16x32_bf16(aq1, b1, s[nt], 0, 0, 0);
    }
    __builtin_amdgcn_s_setprio(0);
#pragma unroll
    for (int nt = 0; nt < 4; ++nt) s[nt] *= 0.125f;
    if (kt == ti) {
#pragma unroll
      for (int nt = 0; nt < 4; ++nt) {
        int col = nt * 16 + rl;
#pragma unroll
        for (int r2 = 0; r2 < 4; ++r2)
          if (col > qloc + r2) s[nt][r2] = -3.0e38f;
      }
    }
#pragma unroll
    for (int r2 = 0; r2 < 4; ++r2) {
      float pm = fmaxf(fmaxf(s[0][r2], s[1][r2]), fmaxf(s[2][r2], s[3][r2]));
#pragma unroll
      for (int o = 1; o < 16; o <<= 1) pm = fmaxf(pm, __shfl_xor(pm, o));
      float mn = fmaxf(m[r2], pm);
      float corr = __expf(m[r2] - mn);
      float p0 = __expf(s[0][r2] - mn);
      float p1 = __expf(s[1][r2] - mn);
      float p2 = __expf(s[2][r2] - mn);
      float p3 = __expf(s[3][r2] - mn);
      float ps = p0 + p1 + p2 + p3;
#pragma unroll
      for (int o = 1; o < 16; o <<= 1) ps += __shfl_xor(ps, o);
      lsum[r2] = lsum[r2] * corr + ps;
      m[r2] = mn;
      oacc[0][r2] *= corr; oacc[1][r2] *= corr;
      oacc[2][r2] *= corr; oacc[3][r2] *= corr;
      int prow = (qloc + r2) * 72;
      Ps[prow + rl]      = f2bf(p0);
      Ps[prow + 16 + rl] = f2bf(p1);
      Ps[prow + 32 + rl] = f2bf(p2);
      Ps[prow + 48 + rl] = f2bf(p3);
    }
    bf16x8 pa0 = *(const bf16x8*)&Ps[(w * 16 + rl) * 72 + g * 8];
    bf16x8 pa1 = *(const bf16x8*)&Ps[(w * 16 + rl) * 72 + 32 + g * 8];
    __builtin_amdgcn_s_setprio(1);
#pragma unroll
    for (int nt = 0; nt < 4; ++nt) {
      int r = (nt * 16 + rl) * 64;
      bf16x8 b0 = *(const bf16x8*)&Vs[cur][r + ((0 + g) ^ sw) * 8];
      bf16x8 b1 = *(const bf16x8*)&Vs[cur][r + ((4 + g) ^ sw) * 8];
      oacc[nt] = __builtin_amdgcn_mfma_f32_16x16x32_bf16(pa0, b0, oacc[nt], 0, 0, 0);
      oacc[nt] = __builtin_amdgcn_mfma_f32_16x16x32_bf16(pa1, b1, oacc[nt], 0, 0, 0);
    }
    __builtin_amdgcn_s_setprio(0);
    __syncthreads();
    cur ^= 1;
  }
  int b = bh / NH, h = bh % NH;
  float invl[4];
#pragma unroll
  for (int r2 = 0; r2 < 4; ++r2) invl[r2] = 1.f / lsum[r2];
#pragma unroll
  for (int nt = 0; nt < 4; ++nt) {
    int d = nt * 16 + rl;
#pragma unroll
    for (int r2 = 0; r2 < 4; ++r2) {
      int trow = ti * 64 + qloc + r2;
      yb[((size_t)(b * SEQ + trow)) * DM + h * HD2 + d] = f2bf(oacc[nt][r2] * invl[r2]);
    }
  }
}

// ======== 256x256 8-phase logits GEMM (T2+T3+T4+T5 template) ================
// 8 waves (2Mx4N), BK=64, 2 K-tile LDS buffers (128 KB), counted vmcnt(4) at
// phases 4/8, per-phase {ds_read || stage} -> barrier -> MFMA -> barrier.
#define LOADA8(BUFA, MH)                                                     \
  {                                                                          \
    _Pragma("unroll") for (int i_ = 0; i_ < 4; ++i_) {                       \
      int row_ = wr * 128 + (MH) * 64 + i_ * 16 + rl;                        \
      _Pragma("unroll") for (int ks_ = 0; ks_ < 2; ++ks_)                    \
          af[i_][ks_] =                                                      \
          *(const bf16x8*)&(BUFA)[row_ * 64 + (((ks_ << 2) + g) ^ sw7) * 8]; \
    }                                                                        \
  }
#define LOADB8(BUFB, NHH, DST)                                               \
  {                                                                          \
    _Pragma("unroll") for (int jf_ = 0; jf_ < 2; ++jf_) {                    \
      int row_ = wc * 64 + (NHH) * 32 + jf_ * 16 + rl;                       \
      _Pragma("unroll") for (int ks_ = 0; ks_ < 2; ++ks_)                    \
          DST[jf_][ks_] =                                                    \
          *(const bf16x8*)&(BUFB)[row_ * 64 + (((ks_ << 2) + g) ^ sw7) * 8]; \
    }                                                                        \
  }
#define STAGEA8(BUFA, T, H)                                                  \
  if ((T) < nT) {                                                            \
    _Pragma("unroll") for (int c_ = 0; c_ < 2; ++c_) {                       \
      int rb_ = c_ * 128 + (H) * 64 + wid * 8;                               \
      glds16(AL + (size_t)(m0 + rb_) * K + (size_t)(T) * 64,                 \
             (BUFA) + rb_ * 64);                                             \
    }                                                                        \
  }
#define STAGEB8(BUFB, T, H)                                                  \
  if ((T) < nT) {                                                            \
    _Pragma("unroll") for (int c_ = 0; c_ < 2; ++c_) {                       \
      int rb_ = (2 * c_ + wr) * 64 + (H) * 32 + wc * 8;                      \
      int sr_ = n0 + rb_ + lhi;                                              \
      if (sr_ >= N) sr_ = N - 1;                                             \
      glds16(Bt + (size_t)sr_ * K + (size_t)(T) * 64 + gsx * 8,              \
             (BUFB) + rb_ * 64);                                             \
    }                                                                        \
  }
#define PHSYNC8                                                              \
  __builtin_amdgcn_sched_barrier(0);                                         \
  __builtin_amdgcn_s_barrier();                                              \
  asm volatile("s_waitcnt lgkmcnt(0)" ::: "memory");                         \
  __builtin_amdgcn_sched_barrier(0);
#define PHMFMA8(MH, NHH, BF)                                                 \
  __builtin_amdgcn_s_setprio(1);                                             \
  _Pragma("unroll") for (int i_ = 0; i_ < 4; ++i_)                           \
  _Pragma("unroll") for (int jf_ = 0; jf_ < 2; ++jf_)                        \
  _Pragma("unroll") for (int ks_ = 0; ks_ < 2; ++ks_)                        \
      acc[(MH)*4 + i_][(NHH)*2 + jf_] =                                      \
      __builtin_amdgcn_mfma_f32_16x16x32_bf16(                               \
          af[i_][ks_], BF[jf_][ks_], acc[(MH)*4 + i_][(NHH)*2 + jf_],        \
          0, 0, 0);                                                          \
  __builtin_amdgcn_s_setprio(0);                                             \
  __builtin_amdgcn_s_barrier();

__global__ __launch_bounds__(512, 2) void k_logits8(
    const u16* __restrict__ A, const u16* __restrict__ Bt,
    float* __restrict__ outf, int M, int N, int K, int MT) {
  __shared__ u16 SM[65536];  // 128 KB: buf0 {A,B}, buf1 {A,B}, 16384 u16 each
  (void)M;
  int nwg = gridDim.x;
  int id = blockIdx.x;
  if ((nwg & 7) == 0) id = (id & 7) * (nwg >> 3) + (id >> 3);  // XCD swizzle
  int mt = id % MT, nt = id / MT;
  int m0 = mt * 256, n0 = nt * 256;
  int tid = threadIdx.x;
  int wid = tid >> 6, l = tid & 63;
  int wr = wid >> 2, wc = wid & 3;
  int rl = l & 15, g = l >> 4, sw7 = rl & 7;
  int lhi = l >> 3;
  int gsx = (l & 7) ^ lhi;
  const u16* AL = A + (size_t)lhi * K + gsx * 8;
  int nT = K >> 6;      // 12 K-tiles of 64
  int nIter = nT >> 1;  // 6 iterations, 2 tiles each
  u16* pA0 = SM;
  u16* pB0 = SM + 16384;
  u16* pA1 = SM + 32768;
  u16* pB1 = SM + 49152;
  f32x4 acc[8][4] = {};
  bf16x8 af[4][2], bf0[2][2], bf1[2][2];
  // prologue: tile0 {A0,B0,A1,B1} -> buf0; tile1 {A0,B0} -> buf1
  STAGEA8(pA0, 0, 0) STAGEB8(pB0, 0, 0) STAGEA8(pA0, 0, 1) STAGEB8(pB0, 0, 1)
  STAGEA8(pA1, 1, 0) STAGEB8(pB1, 1, 0)
  asm volatile("s_waitcnt vmcnt(4)" ::: "memory");
  __builtin_amdgcn_s_barrier();
  for (int it = 0; it < nIter; ++it) {
    int ta = 2 * it, tb = ta + 1;
    bool lastIt = (it + 1 == nIter);
    // ph1: buf0 (0,0) | stage buf1-A1 (tile tb)
    LOADA8(pA0, 0) LOADB8(pB0, 0, bf0) STAGEA8(pA1, tb, 1)
    PHSYNC8 PHMFMA8(0, 0, bf0)
    // ph2: buf0 (0,1) | stage buf1-B1 (tile tb)
    LOADB8(pB0, 1, bf1) STAGEB8(pB1, tb, 1)
    PHSYNC8 PHMFMA8(0, 1, bf1)
    // ph3: buf0 (1,0) | stage buf0-A0 (tile ta+2)
    LOADA8(pA0, 1) STAGEA8(pA0, ta + 2, 0)
    PHSYNC8 PHMFMA8(1, 0, bf0)
    // ph4: buf0 (1,1) | stage buf0-B0 (tile ta+2) | counted vmcnt
    STAGEB8(pB0, ta + 2, 0)
    if (!lastIt) asm volatile("s_waitcnt vmcnt(4)" ::: "memory");
    else         asm volatile("s_waitcnt vmcnt(0)" ::: "memory");
    PHSYNC8 PHMFMA8(1, 1, bf1)
    // ph5: buf1 (0,0) | stage buf0-A1 (tile ta+2)
    LOADA8(pA1, 0) LOADB8(pB1, 0, bf0) STAGEA8(pA0, ta + 2, 1)
    PHSYNC8 PHMFMA8(0, 0, bf0)
    // ph6: buf1 (0,1) | stage buf0-B1 (tile ta+2)
    LOADB8(pB1, 1, bf1) STAGEB8(pB0, ta + 2, 1)
    PHSYNC8 PHMFMA8(0, 1, bf1)
    // ph7: buf1 (1,0) | stage buf1-A0 (tile tb+2)
    LOADA8(pA1, 1) STAGEA8(pA1, tb + 2, 0)
    PHSYNC8 PHMFMA8(1, 0, bf0)
    // ph8: buf1 (1,1) | stage buf1-B0 (tile tb+2) | counted vmcnt
    STAGEB8(pB1, tb + 2, 0)
    if (!lastIt) asm volatile("s_waitcnt vmcnt(4)" ::: "memory");
    PHSYNC8 PHMFMA8(1, 1, bf1)
  }
  // epilogue: 32-row chunks through LDS (alias buf0 as f32 cw[32][260]),
  // coalesced nontemporal f32 row writes
  float* cw = (float*)SM;
  for (int ch = 0; ch < 8; ++ch) {
    __syncthreads();
    if (wr == (ch >> 2)) {
#pragma unroll
      for (int ii = 0; ii < 2; ++ii) {
        int ig = (ch & 3) * 2 + ii;
#pragma unroll
        for (int jg = 0; jg < 4; ++jg) {
          int col = wc * 64 + jg * 16 + rl;
#pragma unroll
          for (int r2 = 0; r2 < 4; ++r2)
            cw[(ii * 16 + g * 4 + r2) * 260 + col] = acc[ig][jg][r2];
        }
      }
    }
    __syncthreads();
    for (int t = tid; t < 8192; t += 512) {
      int rw = t >> 8, col = t & 255;
      int gc = n0 + col;
      if (gc < N)
        __builtin_nontemporal_store(
            cw[rw * 260 + col], &outf[(size_t)(m0 + ch * 32 + rw) * N + gc]);
    }
  }
}

// ------- 64x64-tile GEMM, BK=64, dbuf (round-5 loop), split-K ---------------
// modes: 0 bf16 out; 1 bf16 gelu out; 2 f32 atomic residual add (+bias at sk0)
//        4 fused qkv: rope(q,k) -> qr/kr [bh][t][d]; v -> vT [bh][d][t]
__global__ void k_gemm64(const u16* __restrict__ A, const u16* __restrict__ Bt,
                         const float* __restrict__ bias, u16* __restrict__ outb,
                         float* __restrict__ outf, int M, int N, int K, int MT,
                         int mode, const float* __restrict__ ctab,
                         const float* __restrict__ stab, u16* __restrict__ qrp,
                         u16* __restrict__ krp, u16* __restrict__ vTp) {
  __shared__ u16 SM2[16384];  // As | Bs (2x dbuf); alias f32 cw[64][68] for mode 4
  u16* As = SM2;
  u16* Bs = SM2 + 8192;
  float* cw = (float*)SM2;
  int nwg = gridDim.x;
  int id = blockIdx.x;
  if ((nwg & 7) == 0) id = (id & 7) * (nwg >> 3) + (id >> 3);  // XCD swizzle
  int mt = id % MT, nt = id / MT;
  int sk = blockIdx.y, nsk = gridDim.y;
  int Kc = K / nsk, k0 = sk * Kc;
  int m0 = mt * 64, n0 = nt * 64;
  int tid = threadIdx.x;
  int w = tid >> 6, l = tid & 63;
  int row0 = tid >> 3, slot0 = tid & 7;
  int gs0 = slot0 ^ (row0 & 7);
  const u16* gA0 = A + (size_t)(m0 + row0) * K + k0 + gs0 * 8;
  const u16* gA1 = gA0 + (size_t)32 * K;
  const u16* gB0 = Bt + (size_t)(n0 + row0) * K + k0 + gs0 * 8;
  const u16* gB1 = gB0 + (size_t)32 * K;
  int wm = (w >> 1) * 32, wn = (w & 1) * 32;
  int rl = l & 15, g = l >> 4;
  int sl0 = g ^ (rl & 7), sl1 = (4 + g) ^ (rl & 7);
  f32x4 acc[2][2] = {};
  int nK = Kc >> 6;
  int cur = 0;
  {  // prologue stage kt=0 -> buf0
    glds16(gA0, As + w * 512); glds16(gA1, As + 2048 + w * 512);
    glds16(gB0, Bs + w * 512); glds16(gB1, Bs + 2048 + w * 512);
  }
  __syncthreads();
  for (int kt = 0; kt < nK; ++kt) {
    if (kt + 1 < nK) {
      int nx = (cur ^ 1) * 4096;
      glds16(gA0 + (kt + 1) * 64, As + nx + w * 512);
      glds16(gA1 + (kt + 1) * 64, As + nx + 2048 + w * 512);
      glds16(gB0 + (kt + 1) * 64, Bs + nx + w * 512);
      glds16(gB1 + (kt + 1) * 64, Bs + nx + 2048 + w * 512);
    }
    const u16* Ac = As + cur * 4096;
    const u16* Bc = Bs + cur * 4096;
    bf16x8 a0[2], a1[2], b0[2], b1[2];
    __builtin_amdgcn_s_setprio(1);
#pragma unroll
    for (int i = 0; i < 2; ++i) {
      int r = (wm + i * 16 + rl) * 64;
      a0[i] = *(const bf16x8*)&Ac[r + sl0 * 8];
      a1[i] = *(const bf16x8*)&Ac[r + sl1 * 8];
    }
#pragma unroll
    for (int j = 0; j < 2; ++j) {
      int r = (wn + j * 16 + rl) * 64;
      b0[j] = *(const bf16x8*)&Bc[r + sl0 * 8];
      b1[j] = *(const bf16x8*)&Bc[r + sl1 * 8];
    }
#pragma unroll
    for (int i = 0; i < 2; ++i)
#pragma unroll
      for (int j = 0; j < 2; ++j) {
        acc[i][j] = __builtin_amdgcn_mfma_f32_16x16x32_bf16(a0[i], b0[j],
                                                            acc[i][j], 0, 0, 0);
        acc[i][j] = __builtin_amdgcn_mfma_f32_16x16x32_bf16(a1[i], b1[j],
                                                            acc[i][j], 0, 0, 0);
      }
    __builtin_amdgcn_s_setprio(0);
    __syncthreads();
    cur ^= 1;
  }
  if (mode != 4) {
#pragma unroll
    for (int i = 0; i < 2; ++i) {
#pragma unroll
      for (int j = 0; j < 2; ++j) {
        int col = n0 + wn + j * 16 + rl;
        float bv = bias ? bias[col] : 0.f;
#pragma unroll
        for (int r2 = 0; r2 < 4; ++r2) {
          int row = m0 + wm + i * 16 + g * 4 + r2;
          size_t oi = (size_t)row * N + col;
          float v = acc[i][j][r2];
          if (mode == 0) {
            outb[oi] = f2bf(v + bv);
          } else if (mode == 1) {
            v += bv;
            float u = 0.7978845608028654f * (v + 0.044715f * v * v * v);
            outb[oi] = f2bf(0.5f * v * (1.f + tanhf(u)));
          } else {
            if (sk == 0) v += bv;
            atomicAdd(&outf[oi], v);
          }
        }
      }
    }
    return;
  }
  // ---- mode 4: fused qkv epilogue (tile = 64 tokens x 1 head dim-block) ----
#pragma unroll
  for (int i = 0; i < 2; ++i) {
#pragma unroll
    for (int j = 0; j < 2; ++j) {
      int col = wn + j * 16 + rl;
      float bv = bias[n0 + col];
#pragma unroll
      for (int r2 = 0; r2 < 4; ++r2)
        cw[(wm + i * 16 + g * 4 + r2) * 68 + col] = acc[i][j][r2] + bv;
    }
  }
  __syncthreads();
  int reg = n0 / DM;            // 0=q, 1=k, 2=v  (tiles never straddle regions)
  int h = (n0 % DM) / 64;       // head (tile = exactly one head)
  int b = m0 >> 10;             // SEQ=1024; whole tile same batch
  int t0 = m0 & (SEQ - 1);
  size_t bh = (size_t)(b * NH + h);
  if (reg < 2) {
    u16* dst = (reg == 0) ? qrp : krp;
    for (int t = tid; t < 2048; t += 256) {
      int rowc = t >> 5, cp = t & 31;   // row 0..63, u32-pair 0..31
      int d = 2 * cp;                   // even; pair (d, d+1) same rope class
      int tt = t0 + rowc;
      float x0 = cw[rowc * 68 + d];
      float x1 = cw[rowc * 68 + d + 1];
      float o0, o1;
      if (d < 32) {
        float y0 = cw[rowc * 68 + d + 32];
        float y1 = cw[rowc * 68 + d + 33];
        float c0 = 1.f, s0 = 0.f, c1 = 1.f, s1 = 0.f;
        if (d < 16) {
          c0 = ctab[tt * 16 + d];     s0 = stab[tt * 16 + d];
          c1 = ctab[tt * 16 + d + 1]; s1 = stab[tt * 16 + d + 1];
        }
        o0 = x0 * c0 - y0 * s0;
        o1 = x1 * c1 - y1 * s1;
      } else {
        int j = d - 32;
        float y0 = cw[rowc * 68 + j];
        float y1 = cw[rowc * 68 + j + 1];
        float c0 = 1.f, s0 = 0.f, c1 = 1.f, s1 = 0.f;
        if (j < 16) {
          c0 = ctab[tt * 16 + j];     s0 = stab[tt * 16 + j];
          c1 = ctab[tt * 16 + j + 1]; s1 = stab[tt * 16 + j + 1];
        }
        o0 = x0 * c0 + y0 * s0;
        o1 = x1 * c1 + y1 * s1;
      }
      u32 wv = (u32)f2bf(o0) | ((u32)f2bf(o1) << 16);
      *(u32*)&dst[(bh * SEQ + tt) * HD2 + d] = wv;
    }
  } else {
    // v: transposed write vT[bh][d][t], 2 tokens packed per u32
    for (int t = tid; t < 2048; t += 256) {
      int d = t >> 5, p = t & 31;       // d 0..63, token-pair 0..31
      int tt = t0 + 2 * p;
      u32 wv = (u32)f2bf(cw[(2 * p) * 68 + d]) |
               ((u32)f2bf(cw[(2 * p + 1) * 68 + d]) << 16);
      *(u32*)&vTp[(bh * HD2 + d) * SEQ + tt] = wv;
    }
  }
}

// ---------------- fallback GEMM (f32 B, on-the-fly cvt) — logits only --------
__global__ void k_gemm_f32b(const u16* __restrict__ A, const float* __restrict__ B,
                            float* __restrict__ outf, int M, int N, int K) {
  __shared__ u16 As[128 * 40];
  __shared__ u16 Bs[4 * 128 * 12];
  int tid = threadIdx.x;
  int wid = tid >> 6, lane = tid & 63;
  int rl = lane & 15, g = lane >> 4;
  int m0 = blockIdx.x * 128, n0 = blockIdx.y * 128;
  int wm = (wid >> 1) * 64, wn = (wid & 1) * 64;
  int ar = tid >> 2, ac = tid & 3;
  int bn = tid & 127, bq = tid >> 7;
  f32x4 acc[4][4] = {};
  int nK = K / 32;
  for (int kt = 0; kt < nK; ++kt) {
    __syncthreads();
    {
      const u16* ga = A + (size_t)(m0 + ar) * K + kt * 32 + ac * 8;
      *(uint4*)&As[ar * 40 + ac * 8] = *(const uint4*)ga;
      *(uint4*)&As[(ar + 64) * 40 + ac * 8] = *(const uint4*)(ga + (size_t)64 * K);
    }
    int col = n0 + bn;
#pragma unroll
    for (int r = 0; r < 4; ++r) {
      int kq = bq + 2 * r;
      int kk = kt * 32 + kq * 4;
      float f0 = 0.f, f1 = 0.f, f2v = 0.f, f3 = 0.f;
      if (col < N) {
        const float* gb = B + (size_t)kk * N + col;
        f0 = gb[0]; f1 = gb[(size_t)N]; f2v = gb[(size_t)2 * N]; f3 = gb[(size_t)3 * N];
      }
      uint2 wv;
      wv.x = (u32)f2bf(f0) | ((u32)f2bf(f1) << 16);
      wv.y = (u32)f2bf(f2v) | ((u32)f2bf(f3) << 16);
      *(uint2*)&Bs[(kq >> 1) * 1536 + bn * 12 + (kq & 1) * 4] = wv;
    }
    __syncthreads();
    bf16x8 af[4], bfr[4];
#pragma unroll
    for (int mt = 0; mt < 4; ++mt)
      af[mt] = *(const bf16x8*)&As[(wm + mt * 16 + rl) * 40 + g * 8];
#pragma unroll
    for (int nt = 0; nt < 4; ++nt) {
      const u16* p = &Bs[g * 1536 + (wn + nt * 16 + rl) * 12];
      union { bf16x8 v; uint2 u2[2]; } tmp;
      tmp.u2[0] = *(const uint2*)p;
      tmp.u2[1] = *(const uint2*)(p + 4);
      bfr[nt] = tmp.v;
    }
#pragma unroll
    for (int mt = 0; mt < 4; ++mt)
#pragma unroll
      for (int nt = 0; nt < 4; ++nt)
        acc[mt][nt] = __builtin_amdgcn_mfma_f32_16x16x32_bf16(af[mt], bfr[nt],
                                                              acc[mt][nt], 0, 0, 0);
  }
#pragma unroll
  for (int mt = 0; mt < 4; ++mt)
#pragma unroll
    for (int nt = 0; nt < 4; ++nt) {
      int col = n0 + wn + nt * 16 + rl;
      if (col >= N) continue;
#pragma unroll
      for (int r2 = 0; r2 < 4; ++r2) {
        int row = m0 + wm + mt * 16 + g * 4 + r2;
        outf[(size_t)row * N + col] = acc[mt][nt][r2];
      }
    }
}

extern "C" void kernel_launch(void* const* d_in, const int* in_sizes, int n_in,
                              void* d_out, int out_size, void* d_ws, size_t ws_size,
                              hipStream_t stream) {
  (void)in_sizes; (void)n_in; (void)out_size;
  const int*   idx  = (const int*)  d_in[0];
  const float* wte  = (const float*)d_in[1];
  const float* ln1g = (const float*)d_in[2];
  const float* ln1b = (const float*)d_in[3];
  const float* Wqkv = (const float*)d_in[4];
  const float* bqkv = (const float*)d_in[5];
  const float* Wo   = (const float*)d_in[6];
  const float* bo   = (const float*)d_in[7];
  const float* ln2g = (const float*)d_in[8];
  const float* ln2b = (const float*)d_in[9];
  const float* Wfc  = (const float*)d_in[10];
  const float* bfc  = (const float*)d_in[11];
  const float* Wp   = (const float*)d_in[12];
  const float* bp   = (const float*)d_in[13];
  const float* lnfg = (const float*)d_in[14];
  const float* lnfb = (const float*)d_in[15];
  const float* Wlm  = (const float*)d_in[16];
  float* out = (float*)d_out;

  // Scratch packed into d_out (all dead before the logits GEMM rewrites d_out).
  char* sb = (char*)d_out;
  size_t off = 0;
  auto alloc = [&](size_t bytes) {
    char* p = sb + off;
    off += (bytes + 255) & ~(size_t)255;
    return (void*)p;
  };
  float* xf  = (float*)alloc((size_t)BT * DM * 4);
  u16* h1b   = (u16*)alloc((size_t)BT * DM * 2);
  u16* h2b   = (u16*)alloc((size_t)BT * DM * 2);
  u16* qr    = (u16*)alloc((size_t)BT * DM * 2);
  u16* kr    = (u16*)alloc((size_t)BT * DM * 2);
  u16* vT    = (u16*)alloc((size_t)BT * DM * 2);
  u16* yb    = (u16*)alloc((size_t)BT * DM * 2);
  u16* hgel  = (u16*)alloc((size_t)BT * 4 * DM * 2);
  float* ctab = (float*)alloc((size_t)SEQ * 16 * 4);
  float* stab = (float*)alloc((size_t)SEQ * 16 * 4);
  // transposed bf16 weights (also dead before logits GEMM)
  u16* wqkvT = (u16*)alloc((size_t)NLAYER * 3 * DM * DM * 2);
  u16* woT   = (u16*)alloc((size_t)NLAYER * DM * DM * 2);
  u16* wfcT  = (u16*)alloc((size_t)NLAYER * 4 * DM * DM * 2);
  u16* wpT   = (u16*)alloc((size_t)NLAYER * 4 * DM * DM * 2);

  // Wlm^T (77 MB) must survive the logits GEMM -> d_ws if it fits.
  size_t wlmT_bytes = (size_t)NVOCAB * DM * 2;
  size_t xlnf_bytes = (size_t)BT * DM * 2;
  bool fast_lm = ws_size >= wlmT_bytes + xlnf_bytes + 512;
  u16* wlmT = (u16*)d_ws;
  u16* xlnf = fast_lm ? (u16*)((char*)d_ws + ((wlmT_bytes + 255) & ~(size_t)255))
                      : (u16*)d_ws;

  // ---- weight conversion + trig tables ----
  k_trig<<<(SEQ * 16) / 256, 256, 0, stream>>>(ctab, stab);
  for (int l = 0; l < NLAYER; ++l) {
    k_cvtT<<<dim3((3 * DM + 63) / 64, DM / 64), 256, 0, stream>>>(
        Wqkv + (size_t)l * DM * 3 * DM, wqkvT + (size_t)l * 3 * DM * DM, DM, 3 * DM);
    k_cvtT<<<dim3(DM / 64, DM / 64), 256, 0, stream>>>(
        Wo + (size_t)l * DM * DM, woT + (size_t)l * DM * DM, DM, DM);
    k_cvtT<<<dim3((4 * DM) / 64, DM / 64), 256, 0, stream>>>(
        Wfc + (size_t)l * DM * 4 * DM, wfcT + (size_t)l * 4 * DM * DM, DM, 4 * DM);
    k_cvtT<<<dim3(DM / 64, (4 * DM) / 64), 256, 0, stream>>>(
        Wp + (size_t)l * 4 * DM * DM, wpT + (size_t)l * 4 * DM * DM, 4 * DM, DM);
  }
  if (fast_lm)
    k_cvtT<<<dim3((NVOCAB + 63) / 64, DM / 64), 256, 0, stream>>>(Wlm, wlmT, DM, NVOCAB);

  k_embed<<<BT, 256, 0, stream>>>(idx, wte, xf);
  for (int l = 0; l < NLAYER; ++l) {
    k_ln<<<BT, 256, 0, stream>>>(xf, ln1g + l * DM, ln1b + l * DM,
                                 ln2g + l * DM, ln2b + l * DM, h1b, h2b);
    // fused qkv GEMM + bias + rope + v-transpose
    k_gemm64<<<dim3((BT / 64) * (3 * DM / 64), 1), 256, 0, stream>>>(
        h1b, wqkvT + (size_t)l * 3 * DM * DM, bqkv + (size_t)l * 3 * DM,
        nullptr, nullptr, BT, 3 * DM, DM, BT / 64, 4, ctab, stab, qr, kr, vT);
    k_attn<<<dim3(SEQ / 64, 2 * NH), 256, 0, stream>>>(qr, kr, vT, yb);
    k_gemm64<<<dim3((BT / 64) * (DM / 64), 2), 256, 0, stream>>>(
        yb, woT + (size_t)l * DM * DM, bo + (size_t)l * DM,
        nullptr, xf, BT, DM, DM, BT / 64, 2, nullptr, nullptr, nullptr, nullptr, nullptr);
    k_gemm64<<<dim3((BT / 64) * (4 * DM / 64), 1), 256, 0, stream>>>(
        h2b, wfcT + (size_t)l * 4 * DM * DM, bfc + (size_t)l * 4 * DM,
        hgel, nullptr, BT, 4 * DM, DM, BT / 64, 1, nullptr, nullptr, nullptr, nullptr, nullptr);
    k_gemm64<<<dim3((BT / 64) * (DM / 64), 4), 256, 0, stream>>>(
        hgel, wpT + (size_t)l * 4 * DM * DM, bp + (size_t)l * DM,
        nullptr, xf, BT, DM, 4 * DM, BT / 64, 2, nullptr, nullptr, nullptr, nullptr, nullptr);
  }
  k_ln<<<BT, 256, 0, stream>>>(xf, lnfg, lnfb, nullptr, nullptr, xlnf, nullptr);
  if (fast_lm) {
    int nt = (NVOCAB + 255) / 256;
    k_logits8<<<(BT / 256) * nt, 512, 0, stream>>>(
        xlnf, wlmT, out, BT, NVOCAB, DM, BT / 256);
  } else {
    k_gemm_f32b<<<dim3(BT / 128, (NVOCAB + 127) / 128), 256, 0, stream>>>(
        xlnf, Wlm, out, BT, NVOCAB, DM);
  }
}